// Round 3
// baseline (5600.583 us; speedup 1.0000x reference)
//
#include <hip/hip_runtime.h>
#include <math.h>

// GraphUnet on MI355X.
//  - (A@X)@W+b computed as A@(X@W)+b; pooled A never materialized (composed
//    index gathers rows of original A; column handling via scatter of Z).
//  - top-k via exact rank counting (matches jax.lax.top_k tie-break).
//  - Heavy gemm: fp32 vector (no fp32 MFMA on CDNA4). 8x8 microtile,
//    BM=256 rows x 64 cols, BK=32, 256 threads. A is read DIRECTLY from
//    global into registers (lanes sharing a row broadcast-merge), so LDS
//    only carries the Z tile (double-buffered, async-split staging):
//    per wave-K-tile LDS ~768 cyc < VALU 1024 cyc -> VALU-bound (~2.3x the
//    old LDS-bound 4x8 version per the R2 counter model).
//  - split-K partials + deterministic fused reduce (bias + residual).

#define N0 8192
#define BM 256
#define BK 32

// ---------------------------------------------------------------- small gemm
// Z[oidx?oidx[r]:r] = X1[r,:]@W1 (+ X2[r,:]@W2)   rows x 64, K=64 (per input)
__global__ __launch_bounds__(256) void k_small_gemm(
    const float* __restrict__ X1, const float* __restrict__ W1,
    const float* __restrict__ X2, const float* __restrict__ W2,
    const int* __restrict__ oidx, float* __restrict__ Z, int rows)
{
    __shared__ __align__(16) float Ws1[64][64];
    __shared__ __align__(16) float Ws2[64][64];
    __shared__ __align__(16) float Xs1[32][64];
    __shared__ __align__(16) float Xs2[32][64];
    const int tid = threadIdx.x;
    const int r0 = blockIdx.x * 32;

#pragma unroll
    for (int l = 0; l < 4; ++l) {
        int idx = tid + 256 * l;            // float4 index 0..1023
        int rw = idx >> 4, c4 = (idx & 15) * 4;
        *(float4*)&Ws1[rw][c4] = *(const float4*)(W1 + rw * 64 + c4);
    }
    if (X2) {
#pragma unroll
        for (int l = 0; l < 4; ++l) {
            int idx = tid + 256 * l;
            int rw = idx >> 4, c4 = (idx & 15) * 4;
            *(float4*)&Ws2[rw][c4] = *(const float4*)(W2 + rw * 64 + c4);
        }
    }
#pragma unroll
    for (int l = 0; l < 2; ++l) {
        int idx = tid + 256 * l;            // 0..511
        int rl = idx >> 4, c4 = (idx & 15) * 4;
        int r = r0 + rl;
        float4 v = make_float4(0.f, 0.f, 0.f, 0.f);
        if (r < rows) v = *(const float4*)(X1 + (size_t)r * 64 + c4);
        *(float4*)&Xs1[rl][c4] = v;
        if (X2) {
            float4 v2 = make_float4(0.f, 0.f, 0.f, 0.f);
            if (r < rows) v2 = *(const float4*)(X2 + (size_t)r * 64 + c4);
            *(float4*)&Xs2[rl][c4] = v2;
        }
    }
    __syncthreads();

    const int c = tid & 63;
    const int rg = tid >> 6;                // rows rg*8 .. rg*8+7
    float acc[8] = {0, 0, 0, 0, 0, 0, 0, 0};
#pragma unroll
    for (int k4 = 0; k4 < 16; ++k4) {
        float w0 = Ws1[k4 * 4 + 0][c], w1 = Ws1[k4 * 4 + 1][c];
        float w2 = Ws1[k4 * 4 + 2][c], w3 = Ws1[k4 * 4 + 3][c];
#pragma unroll
        for (int j = 0; j < 8; ++j) {
            float4 x = *(const float4*)&Xs1[rg * 8 + j][k4 * 4];
            acc[j] += x.x * w0 + x.y * w1 + x.z * w2 + x.w * w3;
        }
        if (X2) {
            float u0 = Ws2[k4 * 4 + 0][c], u1 = Ws2[k4 * 4 + 1][c];
            float u2 = Ws2[k4 * 4 + 2][c], u3 = Ws2[k4 * 4 + 3][c];
#pragma unroll
            for (int j = 0; j < 8; ++j) {
                float4 x = *(const float4*)&Xs2[rg * 8 + j][k4 * 4];
                acc[j] += x.x * u0 + x.y * u1 + x.z * u2 + x.w * u3;
            }
        }
    }
#pragma unroll
    for (int j = 0; j < 8; ++j) {
        int r = r0 + rg * 8 + j;
        if (r < rows) {
            int ro = oidx ? oidx[r] : r;
            Z[(size_t)ro * 64 + c] = acc[j];
        }
    }
}

// ----------------------------------------------------------------- big gemm
// P[splitS][r][c] = sum_{k in chunk} A[g(r),k] * Zn[k][c]
// 256 threads: tx=tid&7 (8 cols), ty=tid>>3 (8 rows each) -> 256x64 block.
// A: direct global->register (8 rows/thread; same-row lanes broadcast).
// Z: LDS double-buffer, async-split staged (loads issued before FMA phase).
__global__ __launch_bounds__(256) void k_big_gemm(
    const float* __restrict__ A, const float* __restrict__ Zn,
    const int* __restrict__ gidx, float* __restrict__ P,
    int rows, int kchunk)
{
    __shared__ __align__(16) float Xs[2][BK * 64];   // 16 KB
    const int tid = threadIdx.x;
    const int tx = tid & 7;          // cols tx*8 .. tx*8+7
    const int ty = tid >> 3;         // rows ty*8 .. ty*8+7
    const int r0 = blockIdx.x * BM;
    const int k0 = blockIdx.y * kchunk;
    const int ntiles = kchunk / BK;

    // gathered row pointers (clamped; stores are guarded)
    const float* rowp[8];
#pragma unroll
    for (int i = 0; i < 8; ++i) {
        int r = r0 + ty * 8 + i;
        int rr = (r < rows) ? r : (rows - 1);
        int g = gidx ? gidx[rr] : rr;
        rowp[i] = A + (size_t)g * N0 + k0;
    }

    float acc[8][8];
#pragma unroll
    for (int i = 0; i < 8; ++i)
#pragma unroll
        for (int j = 0; j < 8; ++j) acc[i][j] = 0.f;

    // prologue: stage Z tile 0 (thread stages floats [tid*8, tid*8+8))
    {
        float4 z0 = *(const float4*)(Zn + (size_t)k0 * 64 + tid * 8);
        float4 z1 = *(const float4*)(Zn + (size_t)k0 * 64 + tid * 8 + 4);
        *(float4*)&Xs[0][tid * 8] = z0;
        *(float4*)&Xs[0][tid * 8 + 4] = z1;
    }
    __syncthreads();

    for (int t = 0; t < ntiles; ++t) {
        const int cur = t & 1;
        const int kt = t * BK;
        // async-split: issue next tile's global loads now (in flight under FMA)
        float4 zn0, zn1;
        const bool pf = (t + 1 < ntiles);
        if (pf) {
            const float* src = Zn + (size_t)(k0 + kt + BK) * 64 + tid * 8;
            zn0 = *(const float4*)(src);
            zn1 = *(const float4*)(src + 4);
        }
        // FMA over current tile; A fetched per 4-k group into registers
#pragma unroll
        for (int g = 0; g < 8; ++g) {
            float4 af[8];
#pragma unroll
            for (int i = 0; i < 8; ++i)
                af[i] = *(const float4*)(rowp[i] + kt + g * 4);
#pragma unroll
            for (int q = 0; q < 4; ++q) {
                const int kk = g * 4 + q;
                float4 z0 = *(const float4*)&Xs[cur][kk * 64 + tx * 8];
                float4 z1 = *(const float4*)&Xs[cur][kk * 64 + tx * 8 + 4];
                float zb[8] = {z0.x, z0.y, z0.z, z0.w, z1.x, z1.y, z1.z, z1.w};
#pragma unroll
                for (int i = 0; i < 8; ++i) {
                    float a = (q == 0) ? af[i].x : (q == 1) ? af[i].y
                                       : (q == 2) ? af[i].z : af[i].w;
#pragma unroll
                    for (int j = 0; j < 8; ++j) acc[i][j] += a * zb[j];
                }
            }
        }
        if (pf) {
            *(float4*)&Xs[cur ^ 1][tid * 8] = zn0;
            *(float4*)&Xs[cur ^ 1][tid * 8 + 4] = zn1;
        }
        __syncthreads();
    }

    float* Pp = P + (size_t)blockIdx.y * rows * 64;
#pragma unroll
    for (int i = 0; i < 8; ++i) {
        int r = r0 + ty * 8 + i;
        if (r < rows) {
            float4 v0 = make_float4(acc[i][0], acc[i][1], acc[i][2], acc[i][3]);
            float4 v1 = make_float4(acc[i][4], acc[i][5], acc[i][6], acc[i][7]);
            *(float4*)(Pp + (size_t)r * 64 + tx * 8) = v0;
            *(float4*)(Pp + (size_t)r * 64 + tx * 8 + 4) = v1;
        }
    }
}

// ------------------------------------------------------------------- reduce
// Xout[r][c] = bias[c] (+ resid[r][c]) + sum_s P[s][r][c]
__global__ __launch_bounds__(256) void k_reduce(
    const float* __restrict__ P, int splitK, int rows,
    const float* __restrict__ bias, const float* __restrict__ resid,
    float* __restrict__ Xout)
{
    int t = blockIdx.x * 256 + threadIdx.x;
    if (t >= rows * 16) return;
    int r = t >> 4, c4 = (t & 15) * 4;
    float4 s = *(const float4*)(bias + c4);
    if (resid) {
        float4 d = *(const float4*)(resid + (size_t)r * 64 + c4);
        s.x += d.x; s.y += d.y; s.z += d.z; s.w += d.w;
    }
    const float* p = P + (size_t)r * 64 + c4;
    for (int sp = 0; sp < splitK; ++sp) {
        float4 v = *(const float4*)(p + (size_t)sp * rows * 64);
        s.x += v.x; s.y += v.y; s.z += v.z; s.w += v.w;
    }
    *(float4*)(Xout + (size_t)r * 64 + c4) = s;
}

// -------------------------------------------------------------------- score
// scores[i] = sigmoid((X[i,:]. w + b) / 100)
__global__ __launch_bounds__(256) void k_score(
    const float* __restrict__ X, const float* __restrict__ w,
    const float* __restrict__ bp, float* __restrict__ scores, int n)
{
    __shared__ float ws[64];
    if (threadIdx.x < 64) ws[threadIdx.x] = w[threadIdx.x];
    __syncthreads();
    int r = blockIdx.x * 256 + threadIdx.x;
    if (r >= n) return;
    const float* x = X + (size_t)r * 64;
    float s = 0.f;
#pragma unroll
    for (int k4 = 0; k4 < 16; ++k4) {
        float4 v = *(const float4*)(x + k4 * 4);
        s += v.x * ws[k4 * 4] + v.y * ws[k4 * 4 + 1] +
             v.z * ws[k4 * 4 + 2] + v.w * ws[k4 * 4 + 3];
    }
    s = (s + bp[0]) * 0.01f;
    scores[r] = 1.0f / (1.0f + expf(-s));
}

// --------------------------------------------------------------------- rank
// 32 rows/block, 8 lanes/row. rank(r) = #{j: s_j>s_r or (s_j==s_r and j<r)}.
// If rank<ksel: compact row (scaled by score) + composed index.
__global__ __launch_bounds__(256) void k_rank(
    const float* __restrict__ scores, int n, int ksel,
    const float* __restrict__ Xin, const int* __restrict__ Iold,
    float* __restrict__ Xp, int* __restrict__ Inew)
{
    extern __shared__ float ss[];            // npad floats
    const int npad = (n + 31) & ~31;
    for (int i = threadIdx.x; i < npad; i += 256)
        ss[i] = (i < n) ? scores[i] : -1.0f;
    __syncthreads();

    const int r = blockIdx.x * 32 + (threadIdx.x >> 3);
    const int p = threadIdx.x & 7;
    const float sr = ss[r];                  // r < npad always (grid sizing)
    const int f4per = npad >> 5;             // float4s per lane
    int rank = 0;
    for (int f = p * f4per; f < (p + 1) * f4per; ++f) {
        float4 v = *(const float4*)&ss[f * 4];
        int jb = f * 4;
        rank += (v.x > sr) + (v.y > sr) + (v.z > sr) + (v.w > sr);
        rank += (v.x == sr && (jb + 0) < r);
        rank += (v.y == sr && (jb + 1) < r);
        rank += (v.z == sr && (jb + 2) < r);
        rank += (v.w == sr && (jb + 3) < r);
    }
    rank += __shfl_xor(rank, 1);
    rank += __shfl_xor(rank, 2);
    rank += __shfl_xor(rank, 4);

    if (r < n && rank < ksel) {
        if (p == 0) Inew[rank] = Iold ? Iold[r] : r;
        const float* xi = Xin + (size_t)r * 64;
        float* xo = Xp + (size_t)rank * 64;
        // lane p copies float4s {p, p+8}
#pragma unroll
        for (int h = 0; h < 2; ++h) {
            int f = p + h * 8;
            float4 v = *(const float4*)(xi + f * 4);
            v.x *= sr; v.y *= sr; v.z *= sr; v.w *= sr;
            *(float4*)(xo + f * 4) = v;
        }
    }
}

// --------------------------------------------------------------------- host
static int choose_split(int rows, size_t pbytes)
{
    int br = (rows + BM - 1) / BM;
    int sk = 1;
    while (sk < 64 && br * sk < 512 &&
           (size_t)(sk * 2) * rows * 64 * 4 <= pbytes)
        sk *= 2;
    return sk;
}

extern "C" void kernel_launch(void* const* d_in, const int* in_sizes, int n_in,
                              void* d_out, int out_size, void* d_ws,
                              size_t ws_size, hipStream_t stream)
{
    const float* A   = (const float*)d_in[0];
    const float* X0  = (const float*)d_in[1];
    const float* Wst = (const float*)d_in[2];
    const float* bst = (const float*)d_in[3];
    const float* Wdn = (const float*)d_in[4];   // [4][64][64]
    const float* bdn = (const float*)d_in[5];   // [4][64]
    const float* Wpl = (const float*)d_in[6];   // [4][64]
    const float* bpl = (const float*)d_in[7];   // [4]
    const float* Wbt = (const float*)d_in[8];
    const float* bbt = (const float*)d_in[9];
    const float* Wup = (const float*)d_in[10];  // [4][64][64]
    const float* bup = (const float*)d_in[11];  // [4][64]
    const float* Wen = (const float*)d_in[12];  // [128][64]
    const float* ben = (const float*)d_in[13];

    float* out  = (float*)d_out;
    float* OUT2 = out + (size_t)N0 * 64;        // start_gcn_outs (= org_X)

    char* ws = (char*)d_ws;
    const size_t XBYTES = (size_t)N0 * 64 * 4;  // 2 MB
    float* Zn = (float*)(ws + 0 * XBYTES);
    float* XA = (float*)(ws + 1 * XBYTES);
    float* XB = (float*)(ws + 2 * XBYTES);
    float* D0 = (float*)(ws + 3 * XBYTES);
    float* D1 = (float*)(ws + 4 * XBYTES);
    float* D2 = (float*)(ws + 5 * XBYTES);
    float* D3 = (float*)(ws + 6 * XBYTES);
    float* scores = (float*)(ws + 7 * XBYTES);
    int* I1 = (int*)(ws + 7 * XBYTES + (size_t)N0 * 4);
    int* I2 = I1 + N0;
    int* I3 = I2 + N0;
    int* I4 = I3 + N0;
    float* P = (float*)(ws + 7 * XBYTES + (size_t)N0 * 4 * 5);
    size_t pbytes = ws_size - (7 * XBYTES + (size_t)N0 * 4 * 5);

    // One GCN layer: Xout = A0[gidx] @ scatter(Xin @ W1 (+X2@W2)) + bias (+resid)
    auto gcn = [&](const float* Xin, int rin, const int* sidx,
                   const float* W1, const float* Xin2, const float* W2,
                   const int* gidx, int rout,
                   const float* bias, const float* resid, float* Xout) {
        if (sidx) hipMemsetAsync(Zn, 0, XBYTES, stream);
        k_small_gemm<<<(rin + 31) / 32, 256, 0, stream>>>(Xin, W1, Xin2, W2,
                                                          sidx, Zn, rin);
        int sk = choose_split(rout, pbytes);
        dim3 g((rout + BM - 1) / BM, sk);
        k_big_gemm<<<g, 256, 0, stream>>>(A, Zn, gidx, P, rout, N0 / sk);
        k_reduce<<<((rout * 16) + 255) / 256, 256, 0, stream>>>(
            P, sk, rout, bias, resid, Xout);
    };

    auto poolc = [&](const float* Xlv, int lvl, int n, int ksel,
                     const int* Iold, int* Inew, float* Xp) {
        k_score<<<(n + 255) / 256, 256, 0, stream>>>(Xlv, Wpl + lvl * 64,
                                                     bpl + lvl, scores, n);
        int npad = (n + 31) & ~31;
        k_rank<<<(n + 31) / 32, 256, npad * 4, stream>>>(
            scores, n, ksel, Xlv, Iold, Xp, Inew);
    };

    // sizes: 8192 -> 7372 -> 5160 -> 3096 -> 1548  (int(KS[i]*n) chain)
    // start (also writes org_X / second output)
    gcn(X0, 8192, nullptr, Wst, nullptr, nullptr, nullptr, 8192, bst, nullptr, OUT2);
    // down 0..3 with pools
    gcn(OUT2, 8192, nullptr, Wdn + 0 * 4096, nullptr, nullptr, nullptr, 8192,
        bdn + 0 * 64, nullptr, D0);
    poolc(D0, 0, 8192, 7372, nullptr, I1, XA);
    gcn(XA, 7372, I1, Wdn + 1 * 4096, nullptr, nullptr, I1, 7372,
        bdn + 1 * 64, nullptr, D1);
    poolc(D1, 1, 7372, 5160, I1, I2, XB);
    gcn(XB, 5160, I2, Wdn + 2 * 4096, nullptr, nullptr, I2, 5160,
        bdn + 2 * 64, nullptr, D2);
    poolc(D2, 2, 5160, 3096, I2, I3, XA);
    gcn(XA, 3096, I3, Wdn + 3 * 4096, nullptr, nullptr, I3, 3096,
        bdn + 3 * 64, nullptr, D3);
    poolc(D3, 3, 3096, 1548, I3, I4, XB);
    // bottom
    gcn(XB, 1548, I4, Wbt, nullptr, nullptr, I4, 1548, bbt, nullptr, XA);
    // up (reverse levels, residual = down_outs)
    gcn(XA, 1548, I4, Wup + 0 * 4096, nullptr, nullptr, I3, 3096,
        bup + 0 * 64, D3, XB);
    gcn(XB, 3096, I3, Wup + 1 * 4096, nullptr, nullptr, I2, 5160,
        bup + 1 * 64, D2, XA);
    gcn(XA, 5160, I2, Wup + 2 * 4096, nullptr, nullptr, I1, 7372,
        bup + 2 * 64, D1, XB);
    gcn(XB, 7372, I1, Wup + 3 * 4096, nullptr, nullptr, nullptr, 8192,
        bup + 3 * 64, D0, XA);
    // end: A @ (X @ Wen[0:64] + org_X @ Wen[64:128]) + ben
    gcn(XA, 8192, nullptr, Wen, OUT2, Wen + 64 * 64, nullptr, 8192,
        ben, nullptr, out);
}

// Round 5
// 2678.001 us; speedup vs baseline: 2.0913x; 2.0913x over previous
//
#include <hip/hip_runtime.h>
#include <math.h>

// GraphUnet on MI355X.
//  - (A@X)@W+b computed as A@(X@W)+b; pooled A never materialized (composed
//    index gathers rows of original A; column handling via scatter of Z).
//  - top-k via exact rank counting (matches jax.lax.top_k tie-break).
//  - Heavy gemm: fp32 vector (no fp32 MFMA on CDNA4). BM=256 x 64 cols,
//    BK=32, 256 threads, 8x8 microtile.
//      A: global_load_lds staging (coalesced 128B/row, per-lane gather),
//         XOR-swizzled SOURCE k4-slot keyed on (row>>3)&7 so compute-side
//         ds_read_b128 (column of 8-strided rows) is bank-conflict-free.
//      Z: read directly from global (8KB/tile, L1-resident, broadcast) --
//         keeps the Z traffic OFF the LDS pipe; LDS demand 3072 cyc vs
//         4096 VALU cyc per block-K-tile -> VALU-bound ceiling.
//    (R2 model: 1.5 LDS-B/FLOP -> 57 TF, measured ~60. This: A-only LDS.)
//  - split-K partials + deterministic fused reduce (bias + residual).

#define N0 8192
#define BM 256
#define BK 32

// ---------------------------------------------------------------- small gemm
// Z[oidx?oidx[r]:r] = X1[r,:]@W1 (+ X2[r,:]@W2)   rows x 64, K=64 (per input)
__global__ __launch_bounds__(256) void k_small_gemm(
    const float* __restrict__ X1, const float* __restrict__ W1,
    const float* __restrict__ X2, const float* __restrict__ W2,
    const int* __restrict__ oidx, float* __restrict__ Z, int rows)
{
    __shared__ __align__(16) float Ws1[64][64];
    __shared__ __align__(16) float Ws2[64][64];
    __shared__ __align__(16) float Xs1[32][64];
    __shared__ __align__(16) float Xs2[32][64];
    const int tid = threadIdx.x;
    const int r0 = blockIdx.x * 32;

#pragma unroll
    for (int l = 0; l < 4; ++l) {
        int idx = tid + 256 * l;            // float4 index 0..1023
        int rw = idx >> 4, c4 = (idx & 15) * 4;
        *(float4*)&Ws1[rw][c4] = *(const float4*)(W1 + rw * 64 + c4);
    }
    if (X2) {
#pragma unroll
        for (int l = 0; l < 4; ++l) {
            int idx = tid + 256 * l;
            int rw = idx >> 4, c4 = (idx & 15) * 4;
            *(float4*)&Ws2[rw][c4] = *(const float4*)(W2 + rw * 64 + c4);
        }
    }
#pragma unroll
    for (int l = 0; l < 2; ++l) {
        int idx = tid + 256 * l;            // 0..511
        int rl = idx >> 4, c4 = (idx & 15) * 4;
        int r = r0 + rl;
        float4 v = make_float4(0.f, 0.f, 0.f, 0.f);
        if (r < rows) v = *(const float4*)(X1 + (size_t)r * 64 + c4);
        *(float4*)&Xs1[rl][c4] = v;
        if (X2) {
            float4 v2 = make_float4(0.f, 0.f, 0.f, 0.f);
            if (r < rows) v2 = *(const float4*)(X2 + (size_t)r * 64 + c4);
            *(float4*)&Xs2[rl][c4] = v2;
        }
    }
    __syncthreads();

    const int c = tid & 63;
    const int rg = tid >> 6;                // rows rg*8 .. rg*8+7
    float acc[8] = {0, 0, 0, 0, 0, 0, 0, 0};
#pragma unroll
    for (int k4 = 0; k4 < 16; ++k4) {
        float w0 = Ws1[k4 * 4 + 0][c], w1 = Ws1[k4 * 4 + 1][c];
        float w2 = Ws1[k4 * 4 + 2][c], w3 = Ws1[k4 * 4 + 3][c];
#pragma unroll
        for (int j = 0; j < 8; ++j) {
            float4 x = *(const float4*)&Xs1[rg * 8 + j][k4 * 4];
            acc[j] += x.x * w0 + x.y * w1 + x.z * w2 + x.w * w3;
        }
        if (X2) {
            float u0 = Ws2[k4 * 4 + 0][c], u1 = Ws2[k4 * 4 + 1][c];
            float u2 = Ws2[k4 * 4 + 2][c], u3 = Ws2[k4 * 4 + 3][c];
#pragma unroll
            for (int j = 0; j < 8; ++j) {
                float4 x = *(const float4*)&Xs2[rg * 8 + j][k4 * 4];
                acc[j] += x.x * u0 + x.y * u1 + x.z * u2 + x.w * u3;
            }
        }
    }
#pragma unroll
    for (int j = 0; j < 8; ++j) {
        int r = r0 + rg * 8 + j;
        if (r < rows) {
            int ro = oidx ? oidx[r] : r;
            Z[(size_t)ro * 64 + c] = acc[j];
        }
    }
}

// ----------------------------------------------------------------- big gemm
// P[splitS][r][c] = sum_{k in chunk} A[g(r),k] * Zn[k][c]
// 256 threads: tx=tid&7 (8 cols), ty=tid>>3 (8 rows) -> 256x64 per block.
// A: global_load_lds -> As[256][32] linear, source-XOR-swizzled k4 slots.
// Z: direct global b128 reads (L1-resident 8KB tile).
__global__ __launch_bounds__(256) void k_big_gemm(
    const float* __restrict__ A, const float* __restrict__ Zn,
    const int* __restrict__ gidx, float* __restrict__ P,
    int rows, int kchunk)
{
    __shared__ __align__(16) float As[BM * BK];   // 32 KB, row-major [row][32]
    const int tid = threadIdx.x;
    const int w = tid >> 6, l = tid & 63;
    const int tx = tid & 7;          // cols tx*8 .. tx*8+7
    const int ty = tid >> 3;         // rows ty*8 .. ty*8+7
    const int r0 = blockIdx.x * BM;
    const int k0 = blockIdx.y * kchunk;
    const int ntiles = kchunk / BK;

    // Per-lane A-staging byte offsets (fixed across K-tiles).
    // Instr j stages rows j*32+w*8 .. +8; lane l -> row +(l>>3), k4-slot (l&7).
    // Source swizzle: slot s holds global k4 = s ^ ((row>>3)&7) = s ^ ((j*4+w)&7).
    unsigned goff[8];
#pragma unroll
    for (int j = 0; j < 8; ++j) {
        int R = j * 32 + w * 8 + (l >> 3);
        int r = r0 + R;
        int rr = (r < rows) ? r : rows - 1;
        int g = gidx ? gidx[rr] : rr;
        int sw = (j * 4 + w) & 7;
        goff[j] = (unsigned)g * (unsigned)(N0 * 4) +
                  (unsigned)(k0 + (((l & 7) ^ sw) << 2)) * 4u;
    }

    float acc[8][8];
#pragma unroll
    for (int i = 0; i < 8; ++i)
#pragma unroll
        for (int j = 0; j < 8; ++j) acc[i][j] = 0.f;

    for (int t = 0; t < ntiles; ++t) {
        const unsigned ktb = (unsigned)(t * BK) * 4u;
        // stage A tile: 8 x global_load_lds(16B); LDS dest wave-uniform base,
        // lanes land at base + l*16 (linear) -> As[row][slot].
#pragma unroll
        for (int j = 0; j < 8; ++j)
            __builtin_amdgcn_global_load_lds(
                (const __attribute__((address_space(1))) void*)
                    ((const char*)A + (goff[j] + ktb)),
                (__attribute__((address_space(3))) void*)
                    (&As[j * 1024 + w * 256]),
                16, 0, 0);
        __syncthreads();   // compiler drains vmcnt(0) before barrier -> As ready

        const float* zt = Zn + (size_t)(k0 + t * BK) * 64;
#pragma unroll
        for (int k4 = 0; k4 < 8; ++k4) {
            // A fragments: b128 per row, swizzled slot (conflict-free:
            // bank-quad = ((k4^(ty&7))*4) distinct across the 8 ty of a wave)
            float4 af[8];
            const int slot = ((k4 ^ (ty & 7)) << 2);
#pragma unroll
            for (int i = 0; i < 8; ++i)
                af[i] = *(const float4*)&As[(ty * 8 + i) * 32 + slot];
#pragma unroll
            for (int q = 0; q < 4; ++q) {
                const int kk = k4 * 4 + q;
                float4 z0 = *(const float4*)(zt + kk * 64 + tx * 8);
                float4 z1 = *(const float4*)(zt + kk * 64 + tx * 8 + 4);
                float zb[8] = {z0.x, z0.y, z0.z, z0.w,
                               z1.x, z1.y, z1.z, z1.w};
#pragma unroll
                for (int i = 0; i < 8; ++i) {
                    const float a = (q == 0) ? af[i].x : (q == 1) ? af[i].y
                                   : (q == 2) ? af[i].z : af[i].w;
#pragma unroll
                    for (int j = 0; j < 8; ++j) acc[i][j] += a * zb[j];
                }
            }
        }
        __syncthreads();   // protect As before next overwrite
    }

    float* Pp = P + (size_t)blockIdx.y * rows * 64;
#pragma unroll
    for (int i = 0; i < 8; ++i) {
        int r = r0 + ty * 8 + i;
        if (r < rows) {
            float4 v0 = make_float4(acc[i][0], acc[i][1], acc[i][2], acc[i][3]);
            float4 v1 = make_float4(acc[i][4], acc[i][5], acc[i][6], acc[i][7]);
            *(float4*)(Pp + (size_t)r * 64 + tx * 8) = v0;
            *(float4*)(Pp + (size_t)r * 64 + tx * 8 + 4) = v1;
        }
    }
}

// ------------------------------------------------------------------- reduce
// Xout[r][c] = bias[c] (+ resid[r][c]) + sum_s P[s][r][c]
__global__ __launch_bounds__(256) void k_reduce(
    const float* __restrict__ P, int splitK, int rows,
    const float* __restrict__ bias, const float* __restrict__ resid,
    float* __restrict__ Xout)
{
    int t = blockIdx.x * 256 + threadIdx.x;
    if (t >= rows * 16) return;
    int r = t >> 4, c4 = (t & 15) * 4;
    float4 s = *(const float4*)(bias + c4);
    if (resid) {
        float4 d = *(const float4*)(resid + (size_t)r * 64 + c4);
        s.x += d.x; s.y += d.y; s.z += d.z; s.w += d.w;
    }
    const float* p = P + (size_t)r * 64 + c4;
    for (int sp = 0; sp < splitK; ++sp) {
        float4 v = *(const float4*)(p + (size_t)sp * rows * 64);
        s.x += v.x; s.y += v.y; s.z += v.z; s.w += v.w;
    }
    *(float4*)(Xout + (size_t)r * 64 + c4) = s;
}

// -------------------------------------------------------------------- score
// scores[i] = sigmoid((X[i,:]. w + b) / 100)
__global__ __launch_bounds__(256) void k_score(
    const float* __restrict__ X, const float* __restrict__ w,
    const float* __restrict__ bp, float* __restrict__ scores, int n)
{
    __shared__ float ws[64];
    if (threadIdx.x < 64) ws[threadIdx.x] = w[threadIdx.x];
    __syncthreads();
    int r = blockIdx.x * 256 + threadIdx.x;
    if (r >= n) return;
    const float* x = X + (size_t)r * 64;
    float s = 0.f;
#pragma unroll
    for (int k4 = 0; k4 < 16; ++k4) {
        float4 v = *(const float4*)(x + k4 * 4);
        s += v.x * ws[k4 * 4] + v.y * ws[k4 * 4 + 1] +
             v.z * ws[k4 * 4 + 2] + v.w * ws[k4 * 4 + 3];
    }
    s = (s + bp[0]) * 0.01f;
    scores[r] = 1.0f / (1.0f + expf(-s));
}

// --------------------------------------------------------------------- rank
// 32 rows/block, 8 lanes/row. rank(r) = #{j: s_j>s_r or (s_j==s_r and j<r)}.
// If rank<ksel: compact row (scaled by score) + composed index.
__global__ __launch_bounds__(256) void k_rank(
    const float* __restrict__ scores, int n, int ksel,
    const float* __restrict__ Xin, const int* __restrict__ Iold,
    float* __restrict__ Xp, int* __restrict__ Inew)
{
    extern __shared__ float ss[];            // npad floats
    const int npad = (n + 31) & ~31;
    for (int i = threadIdx.x; i < npad; i += 256)
        ss[i] = (i < n) ? scores[i] : -1.0f;
    __syncthreads();

    const int r = blockIdx.x * 32 + (threadIdx.x >> 3);
    const int p = threadIdx.x & 7;
    const float sr = ss[r];                  // r < npad always (grid sizing)
    const int f4per = npad >> 5;             // float4s per lane
    int rank = 0;
    for (int f = p * f4per; f < (p + 1) * f4per; ++f) {
        float4 v = *(const float4*)&ss[f * 4];
        int jb = f * 4;
        rank += (v.x > sr) + (v.y > sr) + (v.z > sr) + (v.w > sr);
        rank += (v.x == sr && (jb + 0) < r);
        rank += (v.y == sr && (jb + 1) < r);
        rank += (v.z == sr && (jb + 2) < r);
        rank += (v.w == sr && (jb + 3) < r);
    }
    rank += __shfl_xor(rank, 1);
    rank += __shfl_xor(rank, 2);
    rank += __shfl_xor(rank, 4);

    if (r < n && rank < ksel) {
        if (p == 0) Inew[rank] = Iold ? Iold[r] : r;
        const float* xi = Xin + (size_t)r * 64;
        float* xo = Xp + (size_t)rank * 64;
        // lane p copies float4s {p, p+8}
#pragma unroll
        for (int h = 0; h < 2; ++h) {
            int f = p + h * 8;
            float4 v = *(const float4*)(xi + f * 4);
            v.x *= sr; v.y *= sr; v.z *= sr; v.w *= sr;
            *(float4*)(xo + f * 4) = v;
        }
    }
}

// --------------------------------------------------------------------- host
static int choose_split(int rows, size_t pbytes)
{
    int br = (rows + BM - 1) / BM;
    int sk = 1;
    while (sk < 64 && br * sk < 384 &&
           (size_t)(sk * 2) * rows * 64 * 4 <= pbytes)
        sk *= 2;
    return sk;
}

extern "C" void kernel_launch(void* const* d_in, const int* in_sizes, int n_in,
                              void* d_out, int out_size, void* d_ws,
                              size_t ws_size, hipStream_t stream)
{
    const float* A   = (const float*)d_in[0];
    const float* X0  = (const float*)d_in[1];
    const float* Wst = (const float*)d_in[2];
    const float* bst = (const float*)d_in[3];
    const float* Wdn = (const float*)d_in[4];   // [4][64][64]
    const float* bdn = (const float*)d_in[5];   // [4][64]
    const float* Wpl = (const float*)d_in[6];   // [4][64]
    const float* bpl = (const float*)d_in[7];   // [4]
    const float* Wbt = (const float*)d_in[8];
    const float* bbt = (const float*)d_in[9];
    const float* Wup = (const float*)d_in[10];  // [4][64][64]
    const float* bup = (const float*)d_in[11];  // [4][64]
    const float* Wen = (const float*)d_in[12];  // [128][64]
    const float* ben = (const float*)d_in[13];

    float* out  = (float*)d_out;
    float* OUT2 = out + (size_t)N0 * 64;        // start_gcn_outs (= org_X)

    char* ws = (char*)d_ws;
    const size_t XBYTES = (size_t)N0 * 64 * 4;  // 2 MB
    float* Zn = (float*)(ws + 0 * XBYTES);
    float* XA = (float*)(ws + 1 * XBYTES);
    float* XB = (float*)(ws + 2 * XBYTES);
    float* D0 = (float*)(ws + 3 * XBYTES);
    float* D1 = (float*)(ws + 4 * XBYTES);
    float* D2 = (float*)(ws + 5 * XBYTES);
    float* D3 = (float*)(ws + 6 * XBYTES);
    float* scores = (float*)(ws + 7 * XBYTES);
    int* I1 = (int*)(ws + 7 * XBYTES + (size_t)N0 * 4);
    int* I2 = I1 + N0;
    int* I3 = I2 + N0;
    int* I4 = I3 + N0;
    float* P = (float*)(ws + 7 * XBYTES + (size_t)N0 * 4 * 5);
    size_t pbytes = ws_size - (7 * XBYTES + (size_t)N0 * 4 * 5);

    // One GCN layer: Xout = A0[gidx] @ scatter(Xin @ W1 (+X2@W2)) + bias (+resid)
    auto gcn = [&](const float* Xin, int rin, const int* sidx,
                   const float* W1, const float* Xin2, const float* W2,
                   const int* gidx, int rout,
                   const float* bias, const float* resid, float* Xout) {
        if (sidx) hipMemsetAsync(Zn, 0, XBYTES, stream);
        k_small_gemm<<<(rin + 31) / 32, 256, 0, stream>>>(Xin, W1, Xin2, W2,
                                                          sidx, Zn, rin);
        int sk = choose_split(rout, pbytes);
        dim3 g((rout + BM - 1) / BM, sk);
        k_big_gemm<<<g, 256, 0, stream>>>(A, Zn, gidx, P, rout, N0 / sk);
        k_reduce<<<((rout * 16) + 255) / 256, 256, 0, stream>>>(
            P, sk, rout, bias, resid, Xout);
    };

    auto poolc = [&](const float* Xlv, int lvl, int n, int ksel,
                     const int* Iold, int* Inew, float* Xp) {
        k_score<<<(n + 255) / 256, 256, 0, stream>>>(Xlv, Wpl + lvl * 64,
                                                     bpl + lvl, scores, n);
        int npad = (n + 31) & ~31;
        k_rank<<<(n + 31) / 32, 256, npad * 4, stream>>>(
            scores, n, ksel, Xlv, Iold, Xp, Inew);
    };

    // sizes: 8192 -> 7372 -> 5160 -> 3096 -> 1548  (int(KS[i]*n) chain)
    // start (also writes org_X / second output)
    gcn(X0, 8192, nullptr, Wst, nullptr, nullptr, nullptr, 8192, bst, nullptr, OUT2);
    // down 0..3 with pools
    gcn(OUT2, 8192, nullptr, Wdn + 0 * 4096, nullptr, nullptr, nullptr, 8192,
        bdn + 0 * 64, nullptr, D0);
    poolc(D0, 0, 8192, 7372, nullptr, I1, XA);
    gcn(XA, 7372, I1, Wdn + 1 * 4096, nullptr, nullptr, I1, 7372,
        bdn + 1 * 64, nullptr, D1);
    poolc(D1, 1, 7372, 5160, I1, I2, XB);
    gcn(XB, 5160, I2, Wdn + 2 * 4096, nullptr, nullptr, I2, 5160,
        bdn + 2 * 64, nullptr, D2);
    poolc(D2, 2, 5160, 3096, I2, I3, XA);
    gcn(XA, 3096, I3, Wdn + 3 * 4096, nullptr, nullptr, I3, 3096,
        bdn + 3 * 64, nullptr, D3);
    poolc(D3, 3, 3096, 1548, I3, I4, XB);
    // bottom
    gcn(XB, 1548, I4, Wbt, nullptr, nullptr, I4, 1548, bbt, nullptr, XA);
    // up (reverse levels, residual = down_outs)
    gcn(XA, 1548, I4, Wup + 0 * 4096, nullptr, nullptr, I3, 3096,
        bup + 0 * 64, D3, XB);
    gcn(XB, 3096, I3, Wup + 1 * 4096, nullptr, nullptr, I2, 5160,
        bup + 1 * 64, D2, XA);
    gcn(XA, 5160, I2, Wup + 2 * 4096, nullptr, nullptr, I1, 7372,
        bup + 2 * 64, D1, XB);
    gcn(XB, 7372, I1, Wup + 3 * 4096, nullptr, nullptr, nullptr, 8192,
        bup + 3 * 64, D0, XA);
    // end: A @ (X @ Wen[0:64] + org_X @ Wen[64:128]) + ben
    gcn(XA, 8192, nullptr, Wen, OUT2, Wen + 64 * 64, nullptr, 8192,
        ben, nullptr, out);
}

// Round 6
// 1711.975 us; speedup vs baseline: 3.2714x; 1.5643x over previous
//
#include <hip/hip_runtime.h>
#include <math.h>

// GraphUnet on MI355X.
//  - (A@X)@W+b computed as A@(X@W)+b; pooled A never materialized (composed
//    index gathers rows of the original A; columns handled by scatter of Z).
//  - top-k via exact rank counting (matches jax.lax.top_k tie-break).
//  - Heavy gemm: fp32 vector (no fp32 MFMA on CDNA4). BM=256 x 64, BK=32,
//    256 threads, 8x8 microtile. BOTH operands in LDS:
//      A: global_load_lds staging (coalesced, per-lane gather), source-XOR
//         swizzle keyed on (row>>3)&7 -> ds_read_b128 conflict-free
//         (R5-validated: SQ_LDS_BANK_CONFLICT == 0).
//      Z: ALSO staged to LDS (R5 post-mortem: Z-direct-from-global was
//         L1-latency-bound at 22% VALU). 2-way read aliasing = free (m136).
//    LDS model: ~6600 LDS-cyc vs 4096 VALU-cyc per block-K-tile -> ~62%
//    VALU ceiling (~97 TF). Occupancy: 40KB LDS -> 4 blocks/CU; split-K
//    sized so grid >= ~900 blocks.
//  - split-K partials + deterministic fused reduce (bias + residual).

#define N0 8192
#define BM 256
#define BK 32

// ---------------------------------------------------------------- small gemm
// Z[oidx?oidx[r]:r] = X1[r,:]@W1 (+ X2[r,:]@W2)   rows x 64, K=64 (per input)
__global__ __launch_bounds__(256) void k_small_gemm(
    const float* __restrict__ X1, const float* __restrict__ W1,
    const float* __restrict__ X2, const float* __restrict__ W2,
    const int* __restrict__ oidx, float* __restrict__ Z, int rows)
{
    __shared__ __align__(16) float Ws1[64][64];
    __shared__ __align__(16) float Ws2[64][64];
    __shared__ __align__(16) float Xs1[32][64];
    __shared__ __align__(16) float Xs2[32][64];
    const int tid = threadIdx.x;
    const int r0 = blockIdx.x * 32;

#pragma unroll
    for (int l = 0; l < 4; ++l) {
        int idx = tid + 256 * l;            // float4 index 0..1023
        int rw = idx >> 4, c4 = (idx & 15) * 4;
        *(float4*)&Ws1[rw][c4] = *(const float4*)(W1 + rw * 64 + c4);
    }
    if (X2) {
#pragma unroll
        for (int l = 0; l < 4; ++l) {
            int idx = tid + 256 * l;
            int rw = idx >> 4, c4 = (idx & 15) * 4;
            *(float4*)&Ws2[rw][c4] = *(const float4*)(W2 + rw * 64 + c4);
        }
    }
#pragma unroll
    for (int l = 0; l < 2; ++l) {
        int idx = tid + 256 * l;            // 0..511
        int rl = idx >> 4, c4 = (idx & 15) * 4;
        int r = r0 + rl;
        float4 v = make_float4(0.f, 0.f, 0.f, 0.f);
        if (r < rows) v = *(const float4*)(X1 + (size_t)r * 64 + c4);
        *(float4*)&Xs1[rl][c4] = v;
        if (X2) {
            float4 v2 = make_float4(0.f, 0.f, 0.f, 0.f);
            if (r < rows) v2 = *(const float4*)(X2 + (size_t)r * 64 + c4);
            *(float4*)&Xs2[rl][c4] = v2;
        }
    }
    __syncthreads();

    const int c = tid & 63;
    const int rg = tid >> 6;                // rows rg*8 .. rg*8+7
    float acc[8] = {0, 0, 0, 0, 0, 0, 0, 0};
#pragma unroll
    for (int k4 = 0; k4 < 16; ++k4) {
        float w0 = Ws1[k4 * 4 + 0][c], w1 = Ws1[k4 * 4 + 1][c];
        float w2 = Ws1[k4 * 4 + 2][c], w3 = Ws1[k4 * 4 + 3][c];
#pragma unroll
        for (int j = 0; j < 8; ++j) {
            float4 x = *(const float4*)&Xs1[rg * 8 + j][k4 * 4];
            acc[j] += x.x * w0 + x.y * w1 + x.z * w2 + x.w * w3;
        }
        if (X2) {
            float u0 = Ws2[k4 * 4 + 0][c], u1 = Ws2[k4 * 4 + 1][c];
            float u2 = Ws2[k4 * 4 + 2][c], u3 = Ws2[k4 * 4 + 3][c];
#pragma unroll
            for (int j = 0; j < 8; ++j) {
                float4 x = *(const float4*)&Xs2[rg * 8 + j][k4 * 4];
                acc[j] += x.x * u0 + x.y * u1 + x.z * u2 + x.w * u3;
            }
        }
    }
#pragma unroll
    for (int j = 0; j < 8; ++j) {
        int r = r0 + rg * 8 + j;
        if (r < rows) {
            int ro = oidx ? oidx[r] : r;
            Z[(size_t)ro * 64 + c] = acc[j];
        }
    }
}

// ----------------------------------------------------------------- big gemm
// P[splitS][r][c] = sum_{k in chunk} A[g(r),k] * Zn[k][c]
// 256 threads: tx=tid&7 (8 cols), ty=tid>>3 (8 rows) -> 256x64 per block.
// A: global_load_lds -> As[256][32] linear, source-XOR-swizzled k4 slots.
// Z: global_load_lds -> Zs[32][64] linear (2-way read aliasing = free).
__global__ __launch_bounds__(256) void k_big_gemm(
    const float* __restrict__ A, const float* __restrict__ Zn,
    const int* __restrict__ gidx, float* __restrict__ P,
    int rows, int kchunk)
{
    __shared__ __align__(16) float As[BM * BK];   // 32 KB, [row][32] swizzled
    __shared__ __align__(16) float Zs[BK * 64];   // 8 KB, [k][64] linear
    const int tid = threadIdx.x;
    const int w = tid >> 6, l = tid & 63;
    const int tx = tid & 7;          // cols tx*8 .. tx*8+7
    const int ty = tid >> 3;         // rows ty*8 .. ty*8+7
    const int r0 = blockIdx.x * BM;
    const int k0 = blockIdx.y * kchunk;
    const int ntiles = kchunk / BK;

    // Per-lane A-staging byte offsets (fixed across K-tiles).
    // Instr j stages rows j*32+w*8 .. +8; lane l -> row +(l>>3), k4-slot (l&7).
    // Source swizzle: slot s holds global k4 = s ^ ((row>>3)&7) = s ^ ((j*4+w)&7).
    unsigned goff[8];
#pragma unroll
    for (int j = 0; j < 8; ++j) {
        int R = j * 32 + w * 8 + (l >> 3);
        int r = r0 + R;
        int rr = (r < rows) ? r : rows - 1;
        int g = gidx ? gidx[rr] : rr;
        int sw = (j * 4 + w) & 7;
        goff[j] = (unsigned)g * (unsigned)(N0 * 4) +
                  (unsigned)(k0 + (((l & 7) ^ sw) << 2)) * 4u;
    }

    float acc[8][8];
#pragma unroll
    for (int i = 0; i < 8; ++i)
#pragma unroll
        for (int j = 0; j < 8; ++j) acc[i][j] = 0.f;

    for (int t = 0; t < ntiles; ++t) {
        const unsigned ktb = (unsigned)(t * BK) * 4u;
        // stage A tile: 8 x global_load_lds(16B), linear LDS dest per lane
#pragma unroll
        for (int j = 0; j < 8; ++j)
            __builtin_amdgcn_global_load_lds(
                (const __attribute__((address_space(1))) void*)
                    ((const char*)A + (goff[j] + ktb)),
                (__attribute__((address_space(3))) void*)
                    (&As[j * 1024 + w * 256]),
                16, 0, 0);
        // stage Z tile: wave w instr q stages Zs[(w*2+q)*256 .. +256)
        {
            const float* zsrc = Zn + (size_t)(k0 + t * BK) * 64;
#pragma unroll
            for (int q = 0; q < 2; ++q)
                __builtin_amdgcn_global_load_lds(
                    (const __attribute__((address_space(1))) void*)
                        (zsrc + (w * 2 + q) * 256 + l * 4),
                    (__attribute__((address_space(3))) void*)
                        (&Zs[(w * 2 + q) * 256]),
                    16, 0, 0);
        }
        __syncthreads();   // drains vmcnt(0) before barrier -> As,Zs ready

#pragma unroll
        for (int k4 = 0; k4 < 8; ++k4) {
            // A fragments: b128 per row, swizzled slot (conflict-free:
            // bank-quad = ((k4^(ty&7))*4) distinct across the 8 ty of a wave)
            float4 af[8];
            const int slot = ((k4 ^ (ty & 7)) << 2);
#pragma unroll
            for (int i = 0; i < 8; ++i)
                af[i] = *(const float4*)&As[(ty * 8 + i) * 32 + slot];
#pragma unroll
            for (int q = 0; q < 4; ++q) {
                const int kk = k4 * 4 + q;
                float4 z0 = *(const float4*)&Zs[kk * 64 + tx * 8];
                float4 z1 = *(const float4*)&Zs[kk * 64 + tx * 8 + 4];
                float zb[8] = {z0.x, z0.y, z0.z, z0.w,
                               z1.x, z1.y, z1.z, z1.w};
#pragma unroll
                for (int i = 0; i < 8; ++i) {
                    const float a = (q == 0) ? af[i].x : (q == 1) ? af[i].y
                                   : (q == 2) ? af[i].z : af[i].w;
#pragma unroll
                    for (int j = 0; j < 8; ++j) acc[i][j] += a * zb[j];
                }
            }
        }
        __syncthreads();   // protect As/Zs before next overwrite
    }

    float* Pp = P + (size_t)blockIdx.y * rows * 64;
#pragma unroll
    for (int i = 0; i < 8; ++i) {
        int r = r0 + ty * 8 + i;
        if (r < rows) {
            float4 v0 = make_float4(acc[i][0], acc[i][1], acc[i][2], acc[i][3]);
            float4 v1 = make_float4(acc[i][4], acc[i][5], acc[i][6], acc[i][7]);
            *(float4*)(Pp + (size_t)r * 64 + tx * 8) = v0;
            *(float4*)(Pp + (size_t)r * 64 + tx * 8 + 4) = v1;
        }
    }
}

// ------------------------------------------------------------------- reduce
// Xout[r][c] = bias[c] (+ resid[r][c]) + sum_s P[s][r][c]
__global__ __launch_bounds__(256) void k_reduce(
    const float* __restrict__ P, int splitK, int rows,
    const float* __restrict__ bias, const float* __restrict__ resid,
    float* __restrict__ Xout)
{
    int t = blockIdx.x * 256 + threadIdx.x;
    if (t >= rows * 16) return;
    int r = t >> 4, c4 = (t & 15) * 4;
    float4 s = *(const float4*)(bias + c4);
    if (resid) {
        float4 d = *(const float4*)(resid + (size_t)r * 64 + c4);
        s.x += d.x; s.y += d.y; s.z += d.z; s.w += d.w;
    }
    const float* p = P + (size_t)r * 64 + c4;
    for (int sp = 0; sp < splitK; ++sp) {
        float4 v = *(const float4*)(p + (size_t)sp * rows * 64);
        s.x += v.x; s.y += v.y; s.z += v.z; s.w += v.w;
    }
    *(float4*)(Xout + (size_t)r * 64 + c4) = s;
}

// -------------------------------------------------------------------- score
// scores[i] = sigmoid((X[i,:]. w + b) / 100)
__global__ __launch_bounds__(256) void k_score(
    const float* __restrict__ X, const float* __restrict__ w,
    const float* __restrict__ bp, float* __restrict__ scores, int n)
{
    __shared__ float ws[64];
    if (threadIdx.x < 64) ws[threadIdx.x] = w[threadIdx.x];
    __syncthreads();
    int r = blockIdx.x * 256 + threadIdx.x;
    if (r >= n) return;
    const float* x = X + (size_t)r * 64;
    float s = 0.f;
#pragma unroll
    for (int k4 = 0; k4 < 16; ++k4) {
        float4 v = *(const float4*)(x + k4 * 4);
        s += v.x * ws[k4 * 4] + v.y * ws[k4 * 4 + 1] +
             v.z * ws[k4 * 4 + 2] + v.w * ws[k4 * 4 + 3];
    }
    s = (s + bp[0]) * 0.01f;
    scores[r] = 1.0f / (1.0f + expf(-s));
}

// --------------------------------------------------------------------- rank
// 32 rows/block, 8 lanes/row. rank(r) = #{j: s_j>s_r or (s_j==s_r and j<r)}.
// If rank<ksel: compact row (scaled by score) + composed index.
__global__ __launch_bounds__(256) void k_rank(
    const float* __restrict__ scores, int n, int ksel,
    const float* __restrict__ Xin, const int* __restrict__ Iold,
    float* __restrict__ Xp, int* __restrict__ Inew)
{
    extern __shared__ float ss[];            // npad floats
    const int npad = (n + 31) & ~31;
    for (int i = threadIdx.x; i < npad; i += 256)
        ss[i] = (i < n) ? scores[i] : -1.0f;
    __syncthreads();

    const int r = blockIdx.x * 32 + (threadIdx.x >> 3);
    const int p = threadIdx.x & 7;
    const float sr = ss[r];                  // r < npad always (grid sizing)
    const int f4per = npad >> 5;             // float4s per lane
    int rank = 0;
    for (int f = p * f4per; f < (p + 1) * f4per; ++f) {
        float4 v = *(const float4*)&ss[f * 4];
        int jb = f * 4;
        rank += (v.x > sr) + (v.y > sr) + (v.z > sr) + (v.w > sr);
        rank += (v.x == sr && (jb + 0) < r);
        rank += (v.y == sr && (jb + 1) < r);
        rank += (v.z == sr && (jb + 2) < r);
        rank += (v.w == sr && (jb + 3) < r);
    }
    rank += __shfl_xor(rank, 1);
    rank += __shfl_xor(rank, 2);
    rank += __shfl_xor(rank, 4);

    if (r < n && rank < ksel) {
        if (p == 0) Inew[rank] = Iold ? Iold[r] : r;
        const float* xi = Xin + (size_t)r * 64;
        float* xo = Xp + (size_t)rank * 64;
        // lane p copies float4s {p, p+8}
#pragma unroll
        for (int h = 0; h < 2; ++h) {
            int f = p + h * 8;
            float4 v = *(const float4*)(xi + f * 4);
            v.x *= sr; v.y *= sr; v.z *= sr; v.w *= sr;
            *(float4*)(xo + f * 4) = v;
        }
    }
}

// --------------------------------------------------------------------- host
static int choose_split(int rows, size_t pbytes)
{
    int br = (rows + BM - 1) / BM;
    int sk = 1;
    // target >= ~900 blocks (4/CU), keep kchunk >= 64, cap P bytes
    while (sk < 128 && br * sk < 896 && (N0 / (sk * 2)) >= 64 &&
           (size_t)(sk * 2) * rows * 64 * 4 <= pbytes)
        sk *= 2;
    return sk;
}

extern "C" void kernel_launch(void* const* d_in, const int* in_sizes, int n_in,
                              void* d_out, int out_size, void* d_ws,
                              size_t ws_size, hipStream_t stream)
{
    const float* A   = (const float*)d_in[0];
    const float* X0  = (const float*)d_in[1];
    const float* Wst = (const float*)d_in[2];
    const float* bst = (const float*)d_in[3];
    const float* Wdn = (const float*)d_in[4];   // [4][64][64]
    const float* bdn = (const float*)d_in[5];   // [4][64]
    const float* Wpl = (const float*)d_in[6];   // [4][64]
    const float* bpl = (const float*)d_in[7];   // [4]
    const float* Wbt = (const float*)d_in[8];
    const float* bbt = (const float*)d_in[9];
    const float* Wup = (const float*)d_in[10];  // [4][64][64]
    const float* bup = (const float*)d_in[11];  // [4][64]
    const float* Wen = (const float*)d_in[12];  // [128][64]
    const float* ben = (const float*)d_in[13];

    float* out  = (float*)d_out;
    float* OUT2 = out + (size_t)N0 * 64;        // start_gcn_outs (= org_X)

    char* ws = (char*)d_ws;
    const size_t XBYTES = (size_t)N0 * 64 * 4;  // 2 MB
    float* Zn = (float*)(ws + 0 * XBYTES);
    float* XA = (float*)(ws + 1 * XBYTES);
    float* XB = (float*)(ws + 2 * XBYTES);
    float* D0 = (float*)(ws + 3 * XBYTES);
    float* D1 = (float*)(ws + 4 * XBYTES);
    float* D2 = (float*)(ws + 5 * XBYTES);
    float* D3 = (float*)(ws + 6 * XBYTES);
    float* scores = (float*)(ws + 7 * XBYTES);
    int* I1 = (int*)(ws + 7 * XBYTES + (size_t)N0 * 4);
    int* I2 = I1 + N0;
    int* I3 = I2 + N0;
    int* I4 = I3 + N0;
    float* P = (float*)(ws + 7 * XBYTES + (size_t)N0 * 4 * 5);
    size_t pbytes = ws_size - (7 * XBYTES + (size_t)N0 * 4 * 5);

    // One GCN layer: Xout = A0[gidx] @ scatter(Xin @ W1 (+X2@W2)) + bias (+resid)
    auto gcn = [&](const float* Xin, int rin, const int* sidx,
                   const float* W1, const float* Xin2, const float* W2,
                   const int* gidx, int rout,
                   const float* bias, const float* resid, float* Xout) {
        if (sidx) hipMemsetAsync(Zn, 0, XBYTES, stream);
        k_small_gemm<<<(rin + 31) / 32, 256, 0, stream>>>(Xin, W1, Xin2, W2,
                                                          sidx, Zn, rin);
        int sk = choose_split(rout, pbytes);
        dim3 g((rout + BM - 1) / BM, sk);
        k_big_gemm<<<g, 256, 0, stream>>>(A, Zn, gidx, P, rout, N0 / sk);
        k_reduce<<<((rout * 16) + 255) / 256, 256, 0, stream>>>(
            P, sk, rout, bias, resid, Xout);
    };

    auto poolc = [&](const float* Xlv, int lvl, int n, int ksel,
                     const int* Iold, int* Inew, float* Xp) {
        k_score<<<(n + 255) / 256, 256, 0, stream>>>(Xlv, Wpl + lvl * 64,
                                                     bpl + lvl, scores, n);
        int npad = (n + 31) & ~31;
        k_rank<<<(n + 31) / 32, 256, npad * 4, stream>>>(
            scores, n, ksel, Xlv, Iold, Xp, Inew);
    };

    // sizes: 8192 -> 7372 -> 5160 -> 3096 -> 1548  (int(KS[i]*n) chain)
    // start (also writes org_X / second output)
    gcn(X0, 8192, nullptr, Wst, nullptr, nullptr, nullptr, 8192, bst, nullptr, OUT2);
    // down 0..3 with pools
    gcn(OUT2, 8192, nullptr, Wdn + 0 * 4096, nullptr, nullptr, nullptr, 8192,
        bdn + 0 * 64, nullptr, D0);
    poolc(D0, 0, 8192, 7372, nullptr, I1, XA);
    gcn(XA, 7372, I1, Wdn + 1 * 4096, nullptr, nullptr, I1, 7372,
        bdn + 1 * 64, nullptr, D1);
    poolc(D1, 1, 7372, 5160, I1, I2, XB);
    gcn(XB, 5160, I2, Wdn + 2 * 4096, nullptr, nullptr, I2, 5160,
        bdn + 2 * 64, nullptr, D2);
    poolc(D2, 2, 5160, 3096, I2, I3, XA);
    gcn(XA, 3096, I3, Wdn + 3 * 4096, nullptr, nullptr, I3, 3096,
        bdn + 3 * 64, nullptr, D3);
    poolc(D3, 3, 3096, 1548, I3, I4, XB);
    // bottom
    gcn(XB, 1548, I4, Wbt, nullptr, nullptr, I4, 1548, bbt, nullptr, XA);
    // up (reverse levels, residual = down_outs)
    gcn(XA, 1548, I4, Wup + 0 * 4096, nullptr, nullptr, I3, 3096,
        bup + 0 * 64, D3, XB);
    gcn(XB, 3096, I3, Wup + 1 * 4096, nullptr, nullptr, I2, 5160,
        bup + 1 * 64, D2, XA);
    gcn(XA, 5160, I2, Wup + 2 * 4096, nullptr, nullptr, I1, 7372,
        bup + 2 * 64, D1, XB);
    gcn(XB, 7372, I1, Wup + 3 * 4096, nullptr, nullptr, nullptr, 8192,
        bup + 3 * 64, D0, XA);
    // end: A @ (X @ Wen[0:64] + org_X @ Wen[64:128]) + ben
    gcn(XA, 8192, nullptr, Wen, OUT2, Wen + 64 * 64, nullptr, 8192,
        ben, nullptr, out);
}